// Round 6
// baseline (134.007 us; speedup 1.0000x reference)
//
#include <hip/hip_runtime.h>

// Problem constants (fixed by the reference):
//   T = B*C = 4 trees, N = 262144 = 2^18 nodes/tree, HW = 1048576 = 2^20 pixels/tree
#define NT 4
#define NN 262144
#define NMASK (NN - 1)
#define HW 1048576
// 3-level solve: v[i] = c[i] + v[parent[i]], parent[i] < i.
//   k_walkA: [0, KA)   walk to root          (64 blk, latency-bound ~2.6us;
//                                             window 32KB/tree = L1-resident)
//   k_walkB: [KA, KB)  walk until < KA, fold (960 blk, ~2.96 gathers avg;
//                                             fold window 16KB/tree = L1)
//   k_walkC: [KB, NN)  walk until < KB, fold (3072 blk, ~1.85 gathers avg)
// Walk lanes: 0.12M + 0.71M + 1.45M = 2.3M (vs 4.1M for the 2-level round-5).
#define KA 4096
#define KB 65536

// clang ext-vector types: __builtin_nontemporal_load/store accept these
// (HIP's int4/float4 are C++ classes and are rejected).
typedef int   vi4 __attribute__((ext_vector_type(4)));
typedef float vf4 __attribute__((ext_vector_type(4)));

// XCD-locality swizzle (perf heuristic only — correctness never depends on it):
// blocks are dispatched round-robin across 8 XCDs; grp = b&7 is the XCD slot.
// tree = grp>>1 pairs 2 XCDs per tree so each tree's hot data (2MB cmb + 1MB v)
// stays in an 8MB L2 pair. chunk = within-tree block index (bijective for any
// block count divisible by 8).
#define SWIZ(b, tree, chunk)                      \
    int tree  = ((b) & 7) >> 1;                   \
    int chunk = (((b) >> 3) << 1) | ((b) & 1);

// ---------------------------------------------------------------------------
// K1: build packed records {parent, c}, 4 nodes/thread, vec4 streams.
//   c[i] = sigmoid(clip(1000*(attr-thr),-12,12)) * (levels[i]-levels[par])
//   c[root]=levels[0], parent[root]=0.
// attr/parent are single-use -> NT loads; levels is re-read via the gather,
// keep it cached; cmb is re-read by the walks, keep it cached.
// ---------------------------------------------------------------------------
__global__ __launch_bounds__(256, 4) void k_build(
        const float* __restrict__ attr,
        const float* __restrict__ levels,
        const float* __restrict__ thr,
        const int*   __restrict__ parent,
        int2*        __restrict__ cmb) {
    SWIZ(blockIdx.x, tree, chunk)            // 1024 blocks, 256 chunks/tree
    int tb = tree << 18;
    int n0 = (chunk * 256 + threadIdx.x) * 4;    // node within tree
    int i0 = tb + n0;
    vi4 p4 = __builtin_nontemporal_load((const vi4*)(parent + i0));
    vf4 a4 = __builtin_nontemporal_load((const vf4*)(attr + i0));
    vf4 l4 = *(const vf4*)(levels + i0);
    float th = thr[0];
    int2 out[4];
#pragma unroll
    for (int k = 0; k < 4; ++k) {
        int p = p4[k] & NMASK;               // OOB guard
        float lp = levels[tb | p];           // random gather, tree-local (L2)
        float z = 1000.0f * (a4[k] - th);
        z = fminf(fmaxf(z, -12.0f), 12.0f);
        float s = 1.0f / (1.0f + __expf(-z));
        float c = s * (l4[k] - lp);
        if (n0 + k == 0) { c = l4[k]; p = 0; }   // root
        out[k] = make_int2(p, __float_as_int(c));
    }
    vi4 o0 = { out[0].x, out[0].y, out[1].x, out[1].y };
    vi4 o1 = { out[2].x, out[2].y, out[3].x, out[3].y };
    *(vi4*)(cmb + i0)     = o0;
    *(vi4*)(cmb + i0 + 2) = o1;
}

// ---------------------------------------------------------------------------
// K2 (walkA): v[i] for i < KA by walking to the root. All ancestors of node i
// are < i, so chains stay inside cmb[0..KA) = 32KB/tree -> L1-resident on the
// CUs serving it. 64 blocks = 16K concurrent chains; latency-bound at
// max-depth(~25) x hit-latency ~ 2.6us. Avg depth ~7.3.
// ---------------------------------------------------------------------------
__global__ __launch_bounds__(256, 4) void k_walkA(
        const int2* __restrict__ cmb,
        float*      __restrict__ v) {
    SWIZ(blockIdx.x, tree, chunk)            // 64 blocks, 16 chunks/tree
    int tb   = tree << 18;
    int node = chunk * 256 + threadIdx.x;    // 0..KA-1
    const int2* ct = cmb + tb;
    float acc = 0.0f;
    int cur = node;
    bool alive = true;
    for (int it = 0; it < 64 && __any(alive); ++it) {
        if (alive) {
            int2 r = ct[cur];
            acc += __int_as_float(r.y);      // includes levels[0] at the root
            if (cur == 0) alive = false;
            else cur = r.x;                  // r.x < cur < KA
        }
    }
    v[tb + node] = acc;
}

// ---------------------------------------------------------------------------
// K3 (walkB): nodes [KA, KB). Walk until the chain drops below KA (avg ~1.96
// steps), fold the level-A value (16KB/tree window -> L1-hit). Step window
// cmb[0..KB) = 512KB/tree -> L2. 960 blocks, 1 chain/thread.
// ---------------------------------------------------------------------------
__global__ __launch_bounds__(256, 4) void k_walkB(
        const int2* __restrict__ cmb,
        float*      __restrict__ v) {
    SWIZ(blockIdx.x, tree, chunk)            // 960 blocks, 240 chunks/tree
    int tb   = tree << 18;
    int node = KA + chunk * 256 + threadIdx.x;   // KA..KB-1
    const int2*  ct = cmb + tb;
    const float* vt = v + tb;
    float acc = 0.0f;
    int cur = node;
    bool alive = true;
    for (int it = 0; it < 64 && __any(alive); ++it) {
        if (alive) {
            int2 r = ct[cur];                // one 8B gather per step
            acc += __int_as_float(r.y);
            int nxt = r.x;
            if (nxt < KA) { acc += vt[nxt]; alive = false; }
            else cur = nxt;
        }
    }
    v[tb + node] = acc;
}

// ---------------------------------------------------------------------------
// K4 (walkC): nodes [KB, NN). Walk until the chain drops below KB (avg ~0.85
// steps), fold the precomputed value (256KB/tree window, L2-hit). 3072 blocks
// stream across the machine, 1 chain/thread — latency hidden by block supply.
// ---------------------------------------------------------------------------
__global__ __launch_bounds__(256, 4) void k_walkC(
        const int2* __restrict__ cmb,
        float*      __restrict__ v) {
    SWIZ(blockIdx.x, tree, chunk)            // 3072 blocks, 768 chunks/tree
    int tb   = tree << 18;
    int node = KB + chunk * 256 + threadIdx.x;   // KB..NN-1
    const int2*  ct = cmb + tb;
    const float* vt = v + tb;
    float acc = 0.0f;
    int cur = node;
    bool alive = true;
    for (int it = 0; it < 64 && __any(alive); ++it) {
        if (alive) {
            int2 r = ct[cur];                // one 8B gather per step, L2-hit
            acc += __int_as_float(r.y);
            int nxt = r.x;
            if (nxt < KB) { acc += vt[nxt]; alive = false; }
            else cur = nxt;
        }
    }
    v[tb + node] = acc;
}

// ---------------------------------------------------------------------------
// K5: pixel gather  y[t][p] = v[t][pixel_to_node[t][p]], vec4, NT on the
// single-use idx stream and output so v stays L2-resident.
// ---------------------------------------------------------------------------
__global__ __launch_bounds__(256, 4) void k_pix(
        const float* __restrict__ v,
        const int*   __restrict__ p2n,
        float*       __restrict__ y) {
    SWIZ(blockIdx.x, tree, chunk)            // 4096 blocks, 1024 chunks/tree
    int i = (tree << 18) + chunk * 256 + threadIdx.x;  // vec4 index
    vi4 idx = __builtin_nontemporal_load((const vi4*)p2n + i);
    const float* vt = v + (tree << 18);
    vf4 o;
    o.x = vt[idx.x & NMASK];
    o.y = vt[idx.y & NMASK];
    o.z = vt[idx.z & NMASK];
    o.w = vt[idx.w & NMASK];
    __builtin_nontemporal_store(o, (vf4*)y + i);
}

extern "C" void kernel_launch(void* const* d_in, const int* in_sizes, int n_in,
                              void* d_out, int out_size, void* d_ws, size_t ws_size,
                              hipStream_t stream) {
    // setup_inputs order: 0:x (unused), 1:attr_norm, 2:levels, 3:thr, 4:parent, 5:pixel_to_node
    const float* attr   = (const float*)d_in[1];
    const float* levels = (const float*)d_in[2];
    const float* thr    = (const float*)d_in[3];
    const int*   parent = (const int*)d_in[4];
    const int*   p2n    = (const int*)d_in[5];
    float*       y      = (float*)d_out;

    // workspace: cmb = NT*NN int2 (8 MB), v = NT*NN float (4 MB)
    int2*  cmb = (int2*)d_ws;
    float* v   = (float*)((char*)d_ws + (size_t)NT * NN * sizeof(int2));

    k_build<<<NT * NN / 4 / 256, 256, 0, stream>>>(attr, levels, thr, parent, cmb);
    k_walkA<<<NT * KA / 256, 256, 0, stream>>>(cmb, v);
    k_walkB<<<NT * (KB - KA) / 256, 256, 0, stream>>>(cmb, v);
    k_walkC<<<NT * (NN - KB) / 256, 256, 0, stream>>>(cmb, v);
    k_pix  <<<NT * HW / 4 / 256, 256, 0, stream>>>(v, p2n, y);
}

// Round 7
// 130.907 us; speedup vs baseline: 1.0237x; 1.0237x over previous
//
#include <hip/hip_runtime.h>

// Problem constants (fixed by the reference):
//   T = B*C = 4 trees, N = 262144 = 2^18 nodes/tree, HW = 1048576 = 2^20 pixels/tree
#define NT 4
#define NN 262144
#define NMASK (NN - 1)
#define HW 1048576
// 2-level solve: v[i] = c[i] + v[parent[i]], parent[i] < i.
//   k_walkA: [0, KB)  walk to root          (avg depth ~10.7; TA-throughput bound
//                                            at full occupancy, chains L2-resident)
//   k_walkB: [KB, NN) walk until < KB, fold (avg ~1.85 steps + 1 fold gather)
// NOTE (r1/r6 evidence): deeper hierarchies that cut gather-lane count REGRESS —
// walk gathers are latency-hidden at full occupancy; extra dispatches and
// starved latency-bound phases are what cost time. Do not re-split.
#define KB 65536

// clang ext-vector types: __builtin_nontemporal_load/store accept these
// (HIP's int4/float4 are C++ classes and are rejected).
typedef int   vi4 __attribute__((ext_vector_type(4)));
typedef float vf4 __attribute__((ext_vector_type(4)));

// XCD-locality swizzle (perf heuristic only — correctness never depends on it):
// blocks are dispatched round-robin across 8 XCDs; grp = b&7 is the XCD slot.
// tree = grp>>1 pairs 2 XCDs per tree so each tree's hot data (2MB cmb + 1MB v)
// stays in an 8MB L2 pair. chunk = within-tree block index.
#define SWIZ(b, tree, chunk)                      \
    int tree  = ((b) & 7) >> 1;                   \
    int chunk = (((b) >> 3) << 1) | ((b) & 1);

// ---------------------------------------------------------------------------
// K1: build packed records {parent, c}, 4 nodes/thread, vec4 streams.
//   c[i] = sigmoid(clip(1000*(attr-thr),-12,12)) * (levels[i]-levels[par])
//   c[root]=levels[0], parent[root]=0.
// attr/parent are single-use -> NT loads; levels is re-read via the gather,
// keep it cached; cmb is re-read by the walks, keep it cached.
// ---------------------------------------------------------------------------
__global__ __launch_bounds__(256, 4) void k_build(
        const float* __restrict__ attr,
        const float* __restrict__ levels,
        const float* __restrict__ thr,
        const int*   __restrict__ parent,
        int2*        __restrict__ cmb) {
    SWIZ(blockIdx.x, tree, chunk)            // 1024 blocks, 256 chunks/tree
    int tb = tree << 18;
    int n0 = (chunk * 256 + threadIdx.x) * 4;    // node within tree
    int i0 = tb + n0;
    vi4 p4 = __builtin_nontemporal_load((const vi4*)(parent + i0));
    vf4 a4 = __builtin_nontemporal_load((const vf4*)(attr + i0));
    vf4 l4 = *(const vf4*)(levels + i0);
    float th = thr[0];
    int2 out[4];
#pragma unroll
    for (int k = 0; k < 4; ++k) {
        int p = p4[k] & NMASK;               // OOB guard
        float lp = levels[tb | p];           // random gather, tree-local (L2)
        float z = 1000.0f * (a4[k] - th);
        z = fminf(fmaxf(z, -12.0f), 12.0f);
        float s = 1.0f / (1.0f + __expf(-z));
        float c = s * (l4[k] - lp);
        if (n0 + k == 0) { c = l4[k]; p = 0; }   // root
        out[k] = make_int2(p, __float_as_int(c));
    }
    vi4 o0 = { out[0].x, out[0].y, out[1].x, out[1].y };
    vi4 o1 = { out[2].x, out[2].y, out[3].x, out[3].y };
    *(vi4*)(cmb + i0)     = o0;
    *(vi4*)(cmb + i0 + 2) = o1;
}

// ---------------------------------------------------------------------------
// K2 (walkA): v[i] for i < KB by walking to the root. Chains stay inside the
// first KB records (512KB/tree, L2-resident). 1 chain/thread, 1024 blocks =
// 4 blocks/CU on all 256 CUs -> 16 waves/CU hide the ~250cy chain-step
// latency; bound by TA gather throughput (~2.8M lanes / 256 CU ~ 4.6us).
// (1-block/CU variants of this phase are pure serial-latency and regress.)
// ---------------------------------------------------------------------------
__global__ __launch_bounds__(256, 4) void k_walkA(
        const int2* __restrict__ cmb,
        float*      __restrict__ v) {
    SWIZ(blockIdx.x, tree, chunk)            // 1024 blocks, 256 chunks/tree
    int tb   = tree << 18;
    int node = chunk * 256 + threadIdx.x;    // 0..KB-1
    const int2* ct = cmb + tb;
    float acc = 0.0f;
    int cur = node;
    bool alive = true;
    for (int it = 0; it < 64 && __any(alive); ++it) {
        if (alive) {
            int2 r = ct[cur];
            acc += __int_as_float(r.y);      // includes levels[0] at the root
            if (cur == 0) alive = false;
            else cur = r.x;                  // r.x < cur < KB
        }
    }
    v[tb + node] = acc;
}

// ---------------------------------------------------------------------------
// K3 (walkB): nodes [KB, NN). Walk until the chain drops below KB, then fold
// the precomputed value (256KB/tree window, L2-hit). 1 chain/thread, 3072
// blocks stream across the machine — no multi-chain-per-thread lockstep
// serialization, latency hidden by block supply.
// ---------------------------------------------------------------------------
__global__ __launch_bounds__(256, 4) void k_walkB(
        const int2* __restrict__ cmb,
        float*      __restrict__ v) {
    SWIZ(blockIdx.x, tree, chunk)            // 3072 blocks, 768 chunks/tree
    int tb   = tree << 18;
    int node = KB + chunk * 256 + threadIdx.x;   // KB..NN-1
    const int2*  ct = cmb + tb;
    const float* vt = v + tb;
    float acc = 0.0f;
    int cur = node;
    bool alive = true;
    for (int it = 0; it < 64 && __any(alive); ++it) {
        if (alive) {
            int2 r = ct[cur];                // one 8B gather per step, L2-hit
            acc += __int_as_float(r.y);
            int nxt = r.x;
            if (nxt < KB) { acc += vt[nxt]; alive = false; }
            else cur = nxt;
        }
    }
    v[tb + node] = acc;
}

// ---------------------------------------------------------------------------
// K4: pixel gather  y[t][p] = v[t][pixel_to_node[t][p]], vec4, NT on the
// single-use idx stream and output so v stays L2-resident.
// ---------------------------------------------------------------------------
__global__ __launch_bounds__(256, 4) void k_pix(
        const float* __restrict__ v,
        const int*   __restrict__ p2n,
        float*       __restrict__ y) {
    SWIZ(blockIdx.x, tree, chunk)            // 4096 blocks, 1024 chunks/tree
    int i = (tree << 18) + chunk * 256 + threadIdx.x;  // vec4 index
    vi4 idx = __builtin_nontemporal_load((const vi4*)p2n + i);
    const float* vt = v + (tree << 18);
    vf4 o;
    o.x = vt[idx.x & NMASK];
    o.y = vt[idx.y & NMASK];
    o.z = vt[idx.z & NMASK];
    o.w = vt[idx.w & NMASK];
    __builtin_nontemporal_store(o, (vf4*)y + i);
}

extern "C" void kernel_launch(void* const* d_in, const int* in_sizes, int n_in,
                              void* d_out, int out_size, void* d_ws, size_t ws_size,
                              hipStream_t stream) {
    // setup_inputs order: 0:x (unused), 1:attr_norm, 2:levels, 3:thr, 4:parent, 5:pixel_to_node
    const float* attr   = (const float*)d_in[1];
    const float* levels = (const float*)d_in[2];
    const float* thr    = (const float*)d_in[3];
    const int*   parent = (const int*)d_in[4];
    const int*   p2n    = (const int*)d_in[5];
    float*       y      = (float*)d_out;

    // workspace: cmb = NT*NN int2 (8 MB), v = NT*NN float (4 MB)
    int2*  cmb = (int2*)d_ws;
    float* v   = (float*)((char*)d_ws + (size_t)NT * NN * sizeof(int2));

    k_build<<<NT * NN / 4 / 256, 256, 0, stream>>>(attr, levels, thr, parent, cmb);
    k_walkA<<<NT * KB / 256, 256, 0, stream>>>(cmb, v);
    k_walkB<<<NT * (NN - KB) / 256, 256, 0, stream>>>(cmb, v);
    k_pix  <<<NT * HW / 4 / 256, 256, 0, stream>>>(v, p2n, y);
}